// Round 8
// baseline (204.855 us; speedup 1.0000x reference)
//
#include <hip/hip_runtime.h>
#include <math.h>

typedef unsigned short u16;
typedef unsigned char  u8;
typedef unsigned long long u64;
typedef __attribute__((ext_vector_type(8)))  short short8;   // bf16x8 MFMA frag
typedef __attribute__((ext_vector_type(4)))  float f32x4;    // fp32x4 acc frag
typedef __attribute__((ext_vector_type(16))) float f32x16;   // fp32x16 acc frag (32x32)
typedef __attribute__((ext_vector_type(4)))  int   int4v;    // 16B LDS read
typedef __attribute__((ext_vector_type(8)))  int   v8i;      // 32B fp8 operand (K=64)
typedef __attribute__((ext_vector_type(2)))  long  long2v;   // 16B copy

#define NROWS 8192
#define DIM   512
#define EPSF  1e-8f
#define L2E_SCALE 0.063758716f      // log2(e) / sqrt(512)
#define PBIAS 19.0f                 // global 2^-19 bias on P (cancels in normalization)
#define SONE  0x7F7F7F7F            // E8M0 unit scales (2^0) in all bytes

// ---- fp32 -> bf16 (RNE) ----
__device__ __forceinline__ u16 f2b(float x) {
    union { float f; unsigned u; } a; a.f = x;
    unsigned r = (a.u + 0x7fffu + ((a.u >> 16) & 1u)) >> 16;
    return (u16)r;
}
// ---- fp32 -> fp8 e4m3 (OCP on gfx950), RNE via HW cvt ----
__device__ __forceinline__ u8 f2fp8(float x) {
    int p = __builtin_amdgcn_cvt_pk_fp8_f32(x, 0.f, 0, false);
    return (u8)(p & 0xff);
}
// ---- async global -> LDS, 16B per lane ----
__device__ __forceinline__ void ld16(const void* g, void* l) {
    __builtin_amdgcn_global_load_lds(
        (const __attribute__((address_space(1))) void*)g,
        (__attribute__((address_space(3))) void*)l, 16, 0, 0);
}

// 32B MFMA operand as two aliased 16B halves (reads land in consecutive VGPRs)
union op32 { v8i v; int4v h[2]; };

// ================= kernel 0a: x -> xh (bf16) =================
__global__ __launch_bounds__(256) void cvt_kernel(const float* __restrict__ x,
                                                  u16* __restrict__ xh) {
    int idx = (blockIdx.x * 256 + threadIdx.x) * 8;
    float4 a = *(const float4*)(x + idx);
    float4 b = *(const float4*)(x + idx + 4);
    short8 o;
    o[0] = (short)f2b(a.x); o[1] = (short)f2b(a.y);
    o[2] = (short)f2b(a.z); o[3] = (short)f2b(a.w);
    o[4] = (short)f2b(b.x); o[5] = (short)f2b(b.y);
    o[6] = (short)f2b(b.z); o[7] = (short)f2b(b.w);
    *(short8*)(xh + idx) = o;
}

// ================= kernel 0b: W -> W^T bf16 (per 64x64 tile) =================
__global__ __launch_bounds__(256) void wcvt_kernel(const float* __restrict__ Wq,
                                                   const float* __restrict__ Wk,
                                                   const float* __restrict__ Wv,
                                                   u16* __restrict__ wth) {
    const float* W = (blockIdx.z == 0) ? Wq : (blockIdx.z == 1) ? Wk : Wv;
    const int zo = blockIdx.z * DIM * DIM;
    const int k0 = blockIdx.x * 64, n0 = blockIdx.y * 64;
    const int tid = threadIdx.x;
    __shared__ float T[64][65];
    #pragma unroll
    for (int p = 0; p < 4; p++) {
        int r = p * 16 + (tid >> 4);
        int c = (tid & 15) * 4;
        float4 wv = *(const float4*)(W + (size_t)(k0 + r) * DIM + n0 + c);
        T[c + 0][r] = wv.x; T[c + 1][r] = wv.y;
        T[c + 2][r] = wv.z; T[c + 3][r] = wv.w;
    }
    __syncthreads();
    const int n = tid >> 2, kc = (tid & 3) * 16;
    #pragma unroll
    for (int h = 0; h < 2; h++) {
        short8 hv;
        #pragma unroll
        for (int j = 0; j < 8; j++)
            hv[j] = (short)f2b(T[n][kc + h * 8 + j]);
        *(short8*)(wth + zo + (size_t)(n0 + n) * DIM + k0 + kc + h * 8) = hv;
    }
}

// ================= kernel 1: proj, bf16 MFMA -> fp8 outputs (natural k order) =================
// z=0 -> q, z=1 -> k (row-major fp8); z=2 -> vt (transposed).
__global__ __launch_bounds__(256) void proj_kernel(
    const u16* __restrict__ xh, const u16* __restrict__ wth,
    u8* __restrict__ qo, u8* __restrict__ ko, u8* __restrict__ vto)
{
    __shared__ __align__(16) u16 smem[32768];   // 2 bufs x (A 16KB + B 16KB)
    const int z  = blockIdx.z;
    const int zo = z * DIM * DIM;
    const int bn = blockIdx.x * 128;
    const int bm = blockIdx.y * 128;
    const int tid = threadIdx.x;
    const int w = tid >> 6, lane = tid & 63;
    const int wr = w >> 1, wc = w & 1;
    const int nm = lane & 15, quad = lane >> 4;

    f32x4 acc[4][4] = {};

    const u16* ga[4]; const u16* gb[4]; int ldst[4];
    #pragma unroll
    for (int i = 0; i < 4; i++) {
        int lo = i * 4096 + tid * 16;
        int r  = lo >> 7;
        int gs = ((lo >> 4) & 7) ^ (r & 7);
        ldst[i] = lo >> 1;
        ga[i] = xh + (size_t)(bm + r) * DIM + gs * 8;
        gb[i] = wth + zo + (size_t)(bn + r) * DIM + gs * 8;
    }
    int aoff[2], boff[2];
    #pragma unroll
    for (int ks = 0; ks < 2; ks++) {
        int xr = ((ks * 4 + quad) ^ (nm & 7)) << 3;
        aoff[ks] = (wr * 64 + nm) * 64 + xr;
        boff[ks] = 8192 + (wc * 64 + nm) * 64 + xr;
    }

    // prefetch iter 0 -> buf 0
    #pragma unroll
    for (int i = 0; i < 4; i++) ld16(ga[i], smem + ldst[i]);
    #pragma unroll
    for (int i = 0; i < 4; i++) ld16(gb[i], smem + 8192 + ldst[i]);
    #pragma unroll
    for (int i = 0; i < 4; i++) { ga[i] += 64; gb[i] += 64; }

    int cur = 0;
    for (int it = 0; it < 8; it++) {
        __syncthreads();
        if (it < 7) {
            const int nb = (cur ^ 1) << 14;
            #pragma unroll
            for (int i = 0; i < 4; i++) ld16(ga[i], smem + nb + ldst[i]);
            #pragma unroll
            for (int i = 0; i < 4; i++) ld16(gb[i], smem + nb + 8192 + ldst[i]);
            #pragma unroll
            for (int i = 0; i < 4; i++) { ga[i] += 64; gb[i] += 64; }
        }
        const u16* bs = smem + (cur << 14);
        #pragma unroll
        for (int ks = 0; ks < 2; ks++) {
            short8 Af[4], Bf[4];
            #pragma unroll
            for (int ti = 0; ti < 4; ti++)
                Af[ti] = *(const short8*)(bs + aoff[ks] + ti * 1024);
            #pragma unroll
            for (int tj = 0; tj < 4; tj++)
                Bf[tj] = *(const short8*)(bs + boff[ks] + tj * 1024);
            #pragma unroll
            for (int ti = 0; ti < 4; ti++)
                #pragma unroll
                for (int tj = 0; tj < 4; tj++)
                    acc[ti][tj] = __builtin_amdgcn_mfma_f32_16x16x32_bf16(Af[ti], Bf[tj], acc[ti][tj], 0, 0, 0);
        }
        cur ^= 1;
    }

    if (z < 2) {
        u8* y = (z == 0) ? qo : ko;
        #pragma unroll
        for (int ti = 0; ti < 4; ti++)
            #pragma unroll
            for (int tj = 0; tj < 4; tj++) {
                const int cg = bn + wc * 64 + tj * 16 + nm;
                #pragma unroll
                for (int i = 0; i < 4; i++) {
                    int rg = bm + wr * 64 + ti * 16 + quad * 4 + i;
                    y[(size_t)rg * DIM + cg] = f2fp8(fabsf(acc[ti][tj][i]));
                }
            }
    } else {
        __syncthreads();
        u8* Tr = (u8*)smem;    // 128 x 144 bytes
        #pragma unroll
        for (int ti = 0; ti < 4; ti++)
            #pragma unroll
            for (int tj = 0; tj < 4; tj++) {
                const int c = wc * 64 + tj * 16 + nm;
                #pragma unroll
                for (int i = 0; i < 4; i++) {
                    int r = wr * 64 + ti * 16 + quad * 4 + i;
                    Tr[c * 144 + r] = f2fp8(fabsf(acc[ti][tj][i]));
                }
            }
        __syncthreads();
        const int c2 = tid >> 1, hf = tid & 1;
        u8* dst = vto + (size_t)(bn + c2) * NROWS + bm + hf * 64;
        const u8* srcp = Tr + c2 * 144 + hf * 64;
        #pragma unroll
        for (int g = 0; g < 4; g++)
            *(long2v*)(dst + g * 16) = *(const long2v*)(srcp + g * 16);
    }
}

// ================= kernel 2: P = fp8(exp2(c*Q@K^T - 19)), MX-scaled fp8 MFMA =================
// 256x128 tile, 512 thr, BK=128 (4 iters), 48KB single-buffer. Main loop/epilogue = R7
// (measured 60.5us). CHANGED: XCD 2D-banded block decode — each XCD owns a 16nb x 16mb
// band, so its L2 working set = 2MB q + 1MB k = 3MB < 4MB (was 8MB: thrash, L3-latency
// fills at every vmcnt(0) drain). Bijective: 1D grid 2048, xcd=bid&7, g=bid>>3,
// nb=(xcd&3)*16+(g&15), mb=(xcd>>2)*16+(g>>4).
__global__ __launch_bounds__(512) void score_kernel(
    const u8* __restrict__ q, const u8* __restrict__ k,
    u8* __restrict__ P, float* __restrict__ rs_part)
{
    __shared__ __align__(16) u8 smem[49152];    // A 32KB + B 16KB
    __shared__ float rsl[256][2];
    const int bid = blockIdx.x;                 // 2048 blocks
    const int xcd = bid & 7, g = bid >> 3;      // g 0..255
    const int nb = (xcd & 3) * 16 + (g & 15);   // 0..63
    const int mb = (xcd >> 2) * 16 + (g >> 4);  // 0..31
    const int bn = nb * 128;
    const int bm = mb * 256;
    const int tid = threadIdx.x;
    const int w = tid >> 6, lane = tid & 63;
    const int wq = w >> 1, wc = w & 1;
    const int l31 = lane & 31, h = lane >> 5;

    f32x16 acc[2][2] = {};

    const u8* gq[4]; const u8* gk[2]; int lda[4], ldb[2];
    #pragma unroll
    for (int i = 0; i < 4; i++) {
        int lo = i * 8192 + tid * 16;
        int r  = lo >> 7;
        int gs = ((lo >> 4) & 7) ^ (r & 7);
        lda[i] = lo;
        gq[i] = q + (size_t)(bm + r) * DIM + gs * 16;
    }
    #pragma unroll
    for (int i = 0; i < 2; i++) {
        int lo = i * 8192 + tid * 16;
        int r  = lo >> 7;
        int gs = ((lo >> 4) & 7) ^ (r & 7);
        ldb[i] = 32768 + lo;
        gk[i] = k + (size_t)(bn + r) * DIM + gs * 16;
    }
    int offA[2][2][2], offB[2][2][2];
    #pragma unroll
    for (int t = 0; t < 2; t++) {
        int rowA = wq * 64 + t * 32 + l31;
        int rowB = wc * 64 + t * 32 + l31;
        #pragma unroll
        for (int ks = 0; ks < 2; ks++)
            #pragma unroll
            for (int j = 0; j < 2; j++) {
                offA[t][ks][j] = rowA * 128 + (((ks * 4 + h * 2 + j) ^ (rowA & 7)) << 4);
                offB[t][ks][j] = 32768 + rowB * 128 + (((ks * 4 + h * 2 + j) ^ (rowB & 7)) << 4);
            }
    }

    for (int it = 0; it < 4; it++) {
        __syncthreads();                    // prev compute done
        #pragma unroll
        for (int i = 0; i < 4; i++) ld16(gq[i], smem + lda[i]);
        #pragma unroll
        for (int i = 0; i < 2; i++) ld16(gk[i], smem + ldb[i]);
        #pragma unroll
        for (int i = 0; i < 4; i++) gq[i] += 128;
        #pragma unroll
        for (int i = 0; i < 2; i++) gk[i] += 128;
        __syncthreads();                    // staging drained
        #pragma unroll
        for (int ks = 0; ks < 2; ks++) {
            op32 A[2], B[2];
            #pragma unroll
            for (int t = 0; t < 2; t++) {
                A[t].h[0] = *(const int4v*)(smem + offA[t][ks][0]);
                A[t].h[1] = *(const int4v*)(smem + offA[t][ks][1]);
                B[t].h[0] = *(const int4v*)(smem + offB[t][ks][0]);
                B[t].h[1] = *(const int4v*)(smem + offB[t][ks][1]);
            }
            #pragma unroll
            for (int ti = 0; ti < 2; ti++)
                #pragma unroll
                for (int tj = 0; tj < 2; tj++)
                    acc[ti][tj] = __builtin_amdgcn_mfma_scale_f32_32x32x64_f8f6f4(
                        A[ti].v, B[tj].v, acc[ti][tj], 0, 0, 0, SONE, 0, SONE);
        }
    }

    // ---- epilogue: p = min(exp2(s*c - 19), 448), fp8 pk stores, butterfly rowsums ----
    const int bt0 = l31 & 1, bt1 = (l31 >> 1) & 1, bt2 = (l31 >> 2) & 1, bt3 = (l31 >> 3) & 1;
    u8* pbase = P + (size_t)bm * NROWS + bn + wc * 64 + l31;
    #pragma unroll
    for (int ti = 0; ti < 2; ti++) {
        const int rb = wq * 64 + ti * 32 + 4 * h;
        float ps[16];
        #pragma unroll
        for (int rg = 0; rg < 16; rg++) {
            const int row = rb + (rg & 3) + ((rg >> 2) << 3);
            float p0 = fminf(exp2f(fmaf(acc[ti][0][rg], L2E_SCALE, -PBIAS)), 448.0f);
            float p1 = fminf(exp2f(fmaf(acc[ti][1][rg], L2E_SCALE, -PBIAS)), 448.0f);
            int pk = __builtin_amdgcn_cvt_pk_fp8_f32(p0, p1, 0, false);
            u8* pp = pbase + (size_t)row * NROWS;
            pp[0]  = (u8)pk;
            pp[32] = (u8)(((unsigned)pk) >> 8);
            ps[rg] = p0 + p1;
        }
        // butterfly transpose-reduce: fold row-bits b0,b1,b3,b4 into lane bits 0,1,2,3;
        // mask16 completes the 32-col sum (duplicate halves).
        float a8[8], b4v[4], c2[2], d;
        #pragma unroll
        for (int i = 0; i < 8; i++) {
            float mine = bt0 ? ps[2 * i + 1] : ps[2 * i];
            float send = bt0 ? ps[2 * i]     : ps[2 * i + 1];
            a8[i] = mine + __shfl_xor(send, 1);
        }
        #pragma unroll
        for (int i = 0; i < 4; i++) {
            float mine = bt1 ? a8[2 * i + 1] : a8[2 * i];
            float send = bt1 ? a8[2 * i]     : a8[2 * i + 1];
            b4v[i] = mine + __shfl_xor(send, 2);
        }
        #pragma unroll
        for (int i = 0; i < 2; i++) {
            float mine = bt2 ? b4v[2 * i + 1] : b4v[2 * i];
            float send = bt2 ? b4v[2 * i]     : b4v[2 * i + 1];
            c2[i] = mine + __shfl_xor(send, 4);
        }
        {
            float mine = bt3 ? c2[1] : c2[0];
            float send = bt3 ? c2[0] : c2[1];
            d = mine + __shfl_xor(send, 8);
        }
        d += __shfl_xor(d, 16);
        // lane l31 (<16) owns row (l31&3) + 4h + ((l31&12)<<1) within this 32-row tile
        if (l31 < 16)
            rsl[wq * 64 + ti * 32 + (l31 & 3) + 4 * h + ((l31 & 12) << 1)][wc] = d;
    }
    __syncthreads();
    if (tid < 256)
        rs_part[(size_t)nb * NROWS + bm + tid] = rsl[tid][0] + rsl[tid][1];
}

// ================= kernel 3: O_part[s] = P[:, slice_s] @ V[slice_s, :], MX-scaled fp8 =================
// 64x128 tile, 256 thr (4 waves = 2 row x 2 col, each 32x64 of 1x2 32x32). K-split 2,
// BK=128 (32 iters), 24KB LDS. 1024 blocks -> 4 blocks/CU = 16 waves/CU. (unchanged from R7)
__global__ __launch_bounds__(256) void pv_kernel(
    const u8* __restrict__ P, const u8* __restrict__ vt,
    float* __restrict__ part)
{
    __shared__ __align__(16) u8 smem[24576];    // A 64x128 = 8KB + B 128x128 = 16KB
    const int bid = blockIdx.x;
    const int xcd = bid & 7;
    const int g   = bid >> 3;        // 0..127
    const int s   = xcd & 1;
    const int mbg = xcd >> 1;        // 0..3
    const int nb_ = g & 3;
    const int mb  = mbg * 32 + (g >> 2);   // 0..127
    const int bm = mb * 64, bn = nb_ * 128;
    const int kbase = s * 4096;

    const int tid = threadIdx.x;
    const int w = tid >> 6, lane = tid & 63;
    const int wr = w >> 1, wc = w & 1;
    const int l31 = lane & 31, h = lane >> 5;

    f32x16 acc[2] = {};

    const u8* gp[2]; const u8* gv[4]; int lda[2], ldb[4];
    #pragma unroll
    for (int i = 0; i < 2; i++) {
        int lo = i * 4096 + tid * 16;
        int r  = lo >> 7;                       // 0..63
        int gs = ((lo >> 4) & 7) ^ (r & 7);
        lda[i] = lo;
        gp[i] = P + (size_t)(bm + r) * NROWS + kbase + gs * 16;
    }
    #pragma unroll
    for (int i = 0; i < 4; i++) {
        int lo = i * 4096 + tid * 16;
        int r  = lo >> 7;                       // 0..127
        int gs = ((lo >> 4) & 7) ^ (r & 7);
        ldb[i] = 8192 + lo;
        gv[i] = vt + (size_t)(bn + r) * NROWS + kbase + gs * 16;
    }
    int offA[2][2], offB[2][2][2];
    {
        int rowA = wr * 32 + l31;               // 0..63
        #pragma unroll
        for (int ks = 0; ks < 2; ks++)
            #pragma unroll
            for (int j = 0; j < 2; j++)
                offA[ks][j] = rowA * 128 + (((ks * 4 + h * 2 + j) ^ (rowA & 7)) << 4);
    }
    #pragma unroll
    for (int u = 0; u < 2; u++) {
        int rowB = wc * 64 + u * 32 + l31;      // 0..127
        #pragma unroll
        for (int ks = 0; ks < 2; ks++) {
            #pragma unroll
            for (int j = 0; j < 2; j++)
                offB[u][ks][j] = 8192 + rowB * 128 + (((ks * 4 + h * 2 + j) ^ (rowB & 7)) << 4);
        }
    }

    for (int it = 0; it < 32; it++) {
        __syncthreads();
        #pragma unroll
        for (int i = 0; i < 2; i++) ld16(gp[i], smem + lda[i]);
        #pragma unroll
        for (int i = 0; i < 4; i++) ld16(gv[i], smem + ldb[i]);
        #pragma unroll
        for (int i = 0; i < 2; i++) gp[i] += 128;
        #pragma unroll
        for (int i = 0; i < 4; i++) gv[i] += 128;
        __syncthreads();
        #pragma unroll
        for (int ks = 0; ks < 2; ks++) {
            op32 A, B[2];
            A.h[0] = *(const int4v*)(smem + offA[ks][0]);
            A.h[1] = *(const int4v*)(smem + offA[ks][1]);
            #pragma unroll
            for (int u = 0; u < 2; u++) {
                B[u].h[0] = *(const int4v*)(smem + offB[u][ks][0]);
                B[u].h[1] = *(const int4v*)(smem + offB[u][ks][1]);
            }
            #pragma unroll
            for (int u = 0; u < 2; u++)
                acc[u] = __builtin_amdgcn_mfma_scale_f32_32x32x64_f8f6f4(
                    A.v, B[u].v, acc[u], 0, 0, 0, SONE, 0, SONE);
        }
    }

    // ---- epilogue: direct coalesced fp32 partial stores (cols contiguous in lane) ----
    float* ob = part + (size_t)s * NROWS * DIM + (size_t)bm * DIM + bn;
    {
        const int rb = wr * 32 + 4 * h;
        #pragma unroll
        for (int rg = 0; rg < 16; rg++) {
            const int row = rb + (rg & 3) + ((rg >> 2) << 3);
            #pragma unroll
            for (int u = 0; u < 2; u++)
                ob[(size_t)row * DIM + wc * 64 + u * 32 + l31] = acc[u][rg];
        }
    }
}

// ================= kernel 4: out = (part0 + part1) * 1/(rowsum + eps) =================
// 1024 blocks (8 rows each); rowsum gather over 64 lanes + shfl reduce. (unchanged)
__global__ __launch_bounds__(256) void reduce_kernel(
    const float* __restrict__ part, const float* __restrict__ rs_part,
    float* __restrict__ out)
{
    __shared__ float inv_l[8];
    const int r0 = blockIdx.x * 8;
    const int tid = threadIdx.x;
    if (tid < 64) {
        const int rr = tid >> 3, bg = tid & 7;
        float ssum = 0.f;
        #pragma unroll
        for (int b = 0; b < 8; b++)
            ssum += rs_part[(size_t)(bg * 8 + b) * NROWS + r0 + rr];
        ssum += __shfl_xor(ssum, 1);
        ssum += __shfl_xor(ssum, 2);
        ssum += __shfl_xor(ssum, 4);
        if (bg == 0) inv_l[rr] = 1.0f / (ssum + EPSF);
    }
    __syncthreads();
    const int r = r0 + (tid >> 5);
    const int c0 = (tid & 31) * 16;
    const float inv = inv_l[tid >> 5];
    const size_t base = (size_t)r * DIM + c0;
    const size_t NS = (size_t)NROWS * DIM;
    #pragma unroll
    for (int jj = 0; jj < 4; jj++) {
        float4 a0 = *(const float4*)(part + 0 * NS + base + jj * 4);
        float4 a1 = *(const float4*)(part + 1 * NS + base + jj * 4);
        float4 o;
        o.x = (a0.x + a1.x) * inv;
        o.y = (a0.y + a1.y) * inv;
        o.z = (a0.z + a1.z) * inv;
        o.w = (a0.w + a1.w) * inv;
        *(float4*)(out + base + jj * 4) = o;
    }
}

extern "C" void kernel_launch(void* const* d_in, const int* in_sizes, int n_in,
                              void* d_out, int out_size, void* d_ws, size_t ws_size,
                              hipStream_t stream) {
    const float* x  = (const float*)d_in[0];
    const float* Wq = (const float*)d_in[1];
    const float* Wk = (const float*)d_in[2];
    const float* Wv = (const float*)d_in[3];
    float* out = (float*)d_out;

    const size_t XN = (size_t)NROWS * DIM;       // 4.19M elems
    char* ws = (char*)d_ws;
    // layout (bytes):
    //   [0,4M)    q (fp8)    [4M,8M)  k (fp8)    [8M,12M)  vt (fp8)
    //   [12M,14M) rs_part (f32, 64x8192)
    //   [14M,46M) part (f32, 2x8192x512)
    //   [64M,128M) P (fp8, 8192x8192) -- aliases xh/wth (dead after proj)
    u8*    q       = (u8*)(ws);
    u8*    kk      = (u8*)(ws + XN);
    u8*    vt      = (u8*)(ws + 2 * XN);
    float* rs_part = (float*)(ws + 3 * XN);
    float* part    = (float*)(ws + 3 * XN + (64 * NROWS * 4));
    u8*    P       = (u8*)(ws + 64ull * 1024 * 1024);
    u16*   xh      = (u16*)P;
    u16*   wth     = xh + XN;

    cvt_kernel<<<XN / 2048, 256, 0, stream>>>(x, xh);
    wcvt_kernel<<<dim3(8, 8, 3), 256, 0, stream>>>(Wq, Wk, Wv, wth);
    proj_kernel<<<dim3(4, 64, 3), 256, 0, stream>>>(xh, wth, q, kk, vt);
    score_kernel<<<2048, 512, 0, stream>>>(q, kk, P, rs_part);
    pv_kernel<<<1024, 256, 0, stream>>>(P, vt, part);
    reduce_kernel<<<1024, 256, 0, stream>>>(part, rs_part, out);
}

// Round 9
// 185.806 us; speedup vs baseline: 1.1025x; 1.1025x over previous
//
#include <hip/hip_runtime.h>
#include <math.h>

typedef unsigned short u16;
typedef unsigned char  u8;
typedef unsigned long long u64;
typedef __attribute__((ext_vector_type(8)))  short short8;   // bf16x8 MFMA frag
typedef __attribute__((ext_vector_type(4)))  float f32x4;    // fp32x4 acc frag
typedef __attribute__((ext_vector_type(16))) float f32x16;   // fp32x16 acc frag (32x32)
typedef __attribute__((ext_vector_type(4)))  int   int4v;    // 16B LDS read
typedef __attribute__((ext_vector_type(8)))  int   v8i;      // 32B fp8 operand (K=64)
typedef __attribute__((ext_vector_type(2)))  long  long2v;   // 16B copy

#define NROWS 8192
#define DIM   512
#define EPSF  1e-8f
#define L2E_SCALE 0.063758716f      // log2(e) / sqrt(512)
#define PBIAS 19.0f                 // global 2^-19 bias on P (cancels in normalization)
#define SONE  0x7F7F7F7F            // E8M0 unit scales (2^0) in all bytes

// ---- fp32 -> bf16 (RNE) ----
__device__ __forceinline__ u16 f2b(float x) {
    union { float f; unsigned u; } a; a.f = x;
    unsigned r = (a.u + 0x7fffu + ((a.u >> 16) & 1u)) >> 16;
    return (u16)r;
}
// ---- fp32 -> fp8 e4m3 (OCP on gfx950), RNE via HW cvt ----
__device__ __forceinline__ u8 f2fp8(float x) {
    int p = __builtin_amdgcn_cvt_pk_fp8_f32(x, 0.f, 0, false);
    return (u8)(p & 0xff);
}
// ---- raw v_exp_f32 (exp2): inputs bounded; inf clamps via fminf afterwards ----
__device__ __forceinline__ float fexp2(float x) {
    float r; asm("v_exp_f32 %0, %1" : "=v"(r) : "v"(x)); return r;
}
// ---- async global -> LDS, 16B per lane ----
__device__ __forceinline__ void ld16(const void* g, void* l) {
    __builtin_amdgcn_global_load_lds(
        (const __attribute__((address_space(1))) void*)g,
        (__attribute__((address_space(3))) void*)l, 16, 0, 0);
}

// 32B MFMA operand as two aliased 16B halves (reads land in consecutive VGPRs)
union op32 { v8i v; int4v h[2]; };

// ================= kernel 0a: x -> xh (bf16) =================
__global__ __launch_bounds__(256) void cvt_kernel(const float* __restrict__ x,
                                                  u16* __restrict__ xh) {
    int idx = (blockIdx.x * 256 + threadIdx.x) * 8;
    float4 a = *(const float4*)(x + idx);
    float4 b = *(const float4*)(x + idx + 4);
    short8 o;
    o[0] = (short)f2b(a.x); o[1] = (short)f2b(a.y);
    o[2] = (short)f2b(a.z); o[3] = (short)f2b(a.w);
    o[4] = (short)f2b(b.x); o[5] = (short)f2b(b.y);
    o[6] = (short)f2b(b.z); o[7] = (short)f2b(b.w);
    *(short8*)(xh + idx) = o;
}

// ================= kernel 0b: W -> W^T bf16 (per 64x64 tile) =================
__global__ __launch_bounds__(256) void wcvt_kernel(const float* __restrict__ Wq,
                                                   const float* __restrict__ Wk,
                                                   const float* __restrict__ Wv,
                                                   u16* __restrict__ wth) {
    const float* W = (blockIdx.z == 0) ? Wq : (blockIdx.z == 1) ? Wk : Wv;
    const int zo = blockIdx.z * DIM * DIM;
    const int k0 = blockIdx.x * 64, n0 = blockIdx.y * 64;
    const int tid = threadIdx.x;
    __shared__ float T[64][65];
    #pragma unroll
    for (int p = 0; p < 4; p++) {
        int r = p * 16 + (tid >> 4);
        int c = (tid & 15) * 4;
        float4 wv = *(const float4*)(W + (size_t)(k0 + r) * DIM + n0 + c);
        T[c + 0][r] = wv.x; T[c + 1][r] = wv.y;
        T[c + 2][r] = wv.z; T[c + 3][r] = wv.w;
    }
    __syncthreads();
    const int n = tid >> 2, kc = (tid & 3) * 16;
    #pragma unroll
    for (int h = 0; h < 2; h++) {
        short8 hv;
        #pragma unroll
        for (int j = 0; j < 8; j++)
            hv[j] = (short)f2b(T[n][kc + h * 8 + j]);
        *(short8*)(wth + zo + (size_t)(n0 + n) * DIM + k0 + kc + h * 8) = hv;
    }
}

// ================= kernel 1: proj, bf16 MFMA -> fp8 outputs (natural k order) =================
// z=0 -> q, z=1 -> k (row-major fp8); z=2 -> vt (transposed).
__global__ __launch_bounds__(256) void proj_kernel(
    const u16* __restrict__ xh, const u16* __restrict__ wth,
    u8* __restrict__ qo, u8* __restrict__ ko, u8* __restrict__ vto)
{
    __shared__ __align__(16) u16 smem[32768];   // 2 bufs x (A 16KB + B 16KB)
    const int z  = blockIdx.z;
    const int zo = z * DIM * DIM;
    const int bn = blockIdx.x * 128;
    const int bm = blockIdx.y * 128;
    const int tid = threadIdx.x;
    const int w = tid >> 6, lane = tid & 63;
    const int wr = w >> 1, wc = w & 1;
    const int nm = lane & 15, quad = lane >> 4;

    f32x4 acc[4][4] = {};

    const u16* ga[4]; const u16* gb[4]; int ldst[4];
    #pragma unroll
    for (int i = 0; i < 4; i++) {
        int lo = i * 4096 + tid * 16;
        int r  = lo >> 7;
        int gs = ((lo >> 4) & 7) ^ (r & 7);
        ldst[i] = lo >> 1;
        ga[i] = xh + (size_t)(bm + r) * DIM + gs * 8;
        gb[i] = wth + zo + (size_t)(bn + r) * DIM + gs * 8;
    }
    int aoff[2], boff[2];
    #pragma unroll
    for (int ks = 0; ks < 2; ks++) {
        int xr = ((ks * 4 + quad) ^ (nm & 7)) << 3;
        aoff[ks] = (wr * 64 + nm) * 64 + xr;
        boff[ks] = 8192 + (wc * 64 + nm) * 64 + xr;
    }

    // prefetch iter 0 -> buf 0
    #pragma unroll
    for (int i = 0; i < 4; i++) ld16(ga[i], smem + ldst[i]);
    #pragma unroll
    for (int i = 0; i < 4; i++) ld16(gb[i], smem + 8192 + ldst[i]);
    #pragma unroll
    for (int i = 0; i < 4; i++) { ga[i] += 64; gb[i] += 64; }

    int cur = 0;
    for (int it = 0; it < 8; it++) {
        __syncthreads();
        if (it < 7) {
            const int nb = (cur ^ 1) << 14;
            #pragma unroll
            for (int i = 0; i < 4; i++) ld16(ga[i], smem + nb + ldst[i]);
            #pragma unroll
            for (int i = 0; i < 4; i++) ld16(gb[i], smem + nb + 8192 + ldst[i]);
            #pragma unroll
            for (int i = 0; i < 4; i++) { ga[i] += 64; gb[i] += 64; }
        }
        const u16* bs = smem + (cur << 14);
        #pragma unroll
        for (int ks = 0; ks < 2; ks++) {
            short8 Af[4], Bf[4];
            #pragma unroll
            for (int ti = 0; ti < 4; ti++)
                Af[ti] = *(const short8*)(bs + aoff[ks] + ti * 1024);
            #pragma unroll
            for (int tj = 0; tj < 4; tj++)
                Bf[tj] = *(const short8*)(bs + boff[ks] + tj * 1024);
            #pragma unroll
            for (int ti = 0; ti < 4; ti++)
                #pragma unroll
                for (int tj = 0; tj < 4; tj++)
                    acc[ti][tj] = __builtin_amdgcn_mfma_f32_16x16x32_bf16(Af[ti], Bf[tj], acc[ti][tj], 0, 0, 0);
        }
        cur ^= 1;
    }

    if (z < 2) {
        u8* y = (z == 0) ? qo : ko;
        #pragma unroll
        for (int ti = 0; ti < 4; ti++)
            #pragma unroll
            for (int tj = 0; tj < 4; tj++) {
                const int cg = bn + wc * 64 + tj * 16 + nm;
                #pragma unroll
                for (int i = 0; i < 4; i++) {
                    int rg = bm + wr * 64 + ti * 16 + quad * 4 + i;
                    y[(size_t)rg * DIM + cg] = f2fp8(fabsf(acc[ti][tj][i]));
                }
            }
    } else {
        __syncthreads();
        u8* Tr = (u8*)smem;    // 128 x 144 bytes
        #pragma unroll
        for (int ti = 0; ti < 4; ti++)
            #pragma unroll
            for (int tj = 0; tj < 4; tj++) {
                const int c = wc * 64 + tj * 16 + nm;
                #pragma unroll
                for (int i = 0; i < 4; i++) {
                    int r = wr * 64 + ti * 16 + quad * 4 + i;
                    Tr[c * 144 + r] = f2fp8(fabsf(acc[ti][tj][i]));
                }
            }
        __syncthreads();
        const int c2 = tid >> 1, hf = tid & 1;
        u8* dst = vto + (size_t)(bn + c2) * NROWS + bm + hf * 64;
        const u8* srcp = Tr + c2 * 144 + hf * 64;
        #pragma unroll
        for (int g = 0; g < 4; g++)
            *(long2v*)(dst + g * 16) = *(const long2v*)(srcp + g * 16);
    }
}

// ================= kernel 2: P = fp8(exp2(c*Q@K^T - 19)), MX-scaled fp8 MFMA =================
// 256x128 tile, 512 thr, BK=128 (4 iters), 48KB single-buffer, XCD 2D-banded decode
// (R8, measured 58.0us, FETCH 12.4MB). CHANGED: exp2f libcall -> raw v_exp_f32 inline asm
// (inputs bounded; +inf clamps via fminf). Epilogue-only change.
__global__ __launch_bounds__(512) void score_kernel(
    const u8* __restrict__ q, const u8* __restrict__ k,
    u8* __restrict__ P, float* __restrict__ rs_part)
{
    __shared__ __align__(16) u8 smem[49152];    // A 32KB + B 16KB
    __shared__ float rsl[256][2];
    const int bid = blockIdx.x;                 // 2048 blocks
    const int xcd = bid & 7, g = bid >> 3;      // g 0..255
    const int nb = (xcd & 3) * 16 + (g & 15);   // 0..63
    const int mb = (xcd >> 2) * 16 + (g >> 4);  // 0..31
    const int bn = nb * 128;
    const int bm = mb * 256;
    const int tid = threadIdx.x;
    const int w = tid >> 6, lane = tid & 63;
    const int wq = w >> 1, wc = w & 1;
    const int l31 = lane & 31, h = lane >> 5;

    f32x16 acc[2][2] = {};

    const u8* gq[4]; const u8* gk[2]; int lda[4], ldb[2];
    #pragma unroll
    for (int i = 0; i < 4; i++) {
        int lo = i * 8192 + tid * 16;
        int r  = lo >> 7;
        int gs = ((lo >> 4) & 7) ^ (r & 7);
        lda[i] = lo;
        gq[i] = q + (size_t)(bm + r) * DIM + gs * 16;
    }
    #pragma unroll
    for (int i = 0; i < 2; i++) {
        int lo = i * 8192 + tid * 16;
        int r  = lo >> 7;
        int gs = ((lo >> 4) & 7) ^ (r & 7);
        ldb[i] = 32768 + lo;
        gk[i] = k + (size_t)(bn + r) * DIM + gs * 16;
    }
    int offA[2][2][2], offB[2][2][2];
    #pragma unroll
    for (int t = 0; t < 2; t++) {
        int rowA = wq * 64 + t * 32 + l31;
        int rowB = wc * 64 + t * 32 + l31;
        #pragma unroll
        for (int ks = 0; ks < 2; ks++)
            #pragma unroll
            for (int j = 0; j < 2; j++) {
                offA[t][ks][j] = rowA * 128 + (((ks * 4 + h * 2 + j) ^ (rowA & 7)) << 4);
                offB[t][ks][j] = 32768 + rowB * 128 + (((ks * 4 + h * 2 + j) ^ (rowB & 7)) << 4);
            }
    }

    for (int it = 0; it < 4; it++) {
        __syncthreads();                    // prev compute done
        #pragma unroll
        for (int i = 0; i < 4; i++) ld16(gq[i], smem + lda[i]);
        #pragma unroll
        for (int i = 0; i < 2; i++) ld16(gk[i], smem + ldb[i]);
        #pragma unroll
        for (int i = 0; i < 4; i++) gq[i] += 128;
        #pragma unroll
        for (int i = 0; i < 2; i++) gk[i] += 128;
        __syncthreads();                    // staging drained
        #pragma unroll
        for (int ks = 0; ks < 2; ks++) {
            op32 A[2], B[2];
            #pragma unroll
            for (int t = 0; t < 2; t++) {
                A[t].h[0] = *(const int4v*)(smem + offA[t][ks][0]);
                A[t].h[1] = *(const int4v*)(smem + offA[t][ks][1]);
                B[t].h[0] = *(const int4v*)(smem + offB[t][ks][0]);
                B[t].h[1] = *(const int4v*)(smem + offB[t][ks][1]);
            }
            #pragma unroll
            for (int ti = 0; ti < 2; ti++)
                #pragma unroll
                for (int tj = 0; tj < 2; tj++)
                    acc[ti][tj] = __builtin_amdgcn_mfma_scale_f32_32x32x64_f8f6f4(
                        A[ti].v, B[tj].v, acc[ti][tj], 0, 0, 0, SONE, 0, SONE);
        }
    }

    // ---- epilogue: p = min(exp2(s*c - 19), 448), fp8 pk stores, butterfly rowsums ----
    const int bt0 = l31 & 1, bt1 = (l31 >> 1) & 1, bt2 = (l31 >> 2) & 1, bt3 = (l31 >> 3) & 1;
    u8* pbase = P + (size_t)bm * NROWS + bn + wc * 64 + l31;
    #pragma unroll
    for (int ti = 0; ti < 2; ti++) {
        const int rb = wq * 64 + ti * 32 + 4 * h;
        float ps[16];
        #pragma unroll
        for (int rg = 0; rg < 16; rg++) {
            const int row = rb + (rg & 3) + ((rg >> 2) << 3);
            float p0 = fminf(fexp2(fmaf(acc[ti][0][rg], L2E_SCALE, -PBIAS)), 448.0f);
            float p1 = fminf(fexp2(fmaf(acc[ti][1][rg], L2E_SCALE, -PBIAS)), 448.0f);
            int pk = __builtin_amdgcn_cvt_pk_fp8_f32(p0, p1, 0, false);
            u8* pp = pbase + (size_t)row * NROWS;
            pp[0]  = (u8)pk;
            pp[32] = (u8)(((unsigned)pk) >> 8);
            ps[rg] = p0 + p1;
        }
        // butterfly transpose-reduce: fold row-bits b0,b1,b3,b4 into lane bits 0,1,2,3;
        // mask16 completes the 32-col sum (duplicate halves).
        float a8[8], b4v[4], c2[2], d;
        #pragma unroll
        for (int i = 0; i < 8; i++) {
            float mine = bt0 ? ps[2 * i + 1] : ps[2 * i];
            float send = bt0 ? ps[2 * i]     : ps[2 * i + 1];
            a8[i] = mine + __shfl_xor(send, 1);
        }
        #pragma unroll
        for (int i = 0; i < 4; i++) {
            float mine = bt1 ? a8[2 * i + 1] : a8[2 * i];
            float send = bt1 ? a8[2 * i]     : a8[2 * i + 1];
            b4v[i] = mine + __shfl_xor(send, 2);
        }
        #pragma unroll
        for (int i = 0; i < 2; i++) {
            float mine = bt2 ? b4v[2 * i + 1] : b4v[2 * i];
            float send = bt2 ? b4v[2 * i]     : b4v[2 * i + 1];
            c2[i] = mine + __shfl_xor(send, 4);
        }
        {
            float mine = bt3 ? c2[1] : c2[0];
            float send = bt3 ? c2[0] : c2[1];
            d = mine + __shfl_xor(send, 8);
        }
        d += __shfl_xor(d, 16);
        // lane l31 (<16) owns row (l31&3) + 4h + ((l31&12)<<1) within this 32-row tile
        if (l31 < 16)
            rsl[wq * 64 + ti * 32 + (l31 & 3) + 4 * h + ((l31 & 12) << 1)][wc] = d;
    }
    __syncthreads();
    if (tid < 256)
        rs_part[(size_t)nb * NROWS + bm + tid] = rsl[tid][0] + rsl[tid][1];
}

// ================= kernel 3: O_part[s] = P[:, slice_s] @ V[slice_s, :], MX-scaled fp8 =================
// REVERTED to R5 geometry: 128x128 tile, 256 thr (4 waves 2x2, each 64x64 of 2x2 32x32).
// K-split 2, BK=128 (32 iters), 32KB LDS, 512 blocks, XCD decode. Rationale: 16 ds_reads
// per 8 MFMA (2:1) vs R6-shape's 12:4 (3:1) — ~33% fewer LDS-pipe cycles per MFMA, and
// the LDS pipe is the measured bottleneck class for these kernels.
__global__ __launch_bounds__(256) void pv_kernel(
    const u8* __restrict__ P, const u8* __restrict__ vt,
    float* __restrict__ part)
{
    __shared__ __align__(16) u8 smem[32768];    // A 16KB + B 16KB
    const int bid = blockIdx.x;
    const int xcd = bid & 7;
    const int g   = bid >> 3;        // 0..63
    const int s   = xcd & 1;
    const int mbg = xcd >> 1;        // 0..3
    const int nb_ = g & 3;
    const int mb  = mbg * 16 + (g >> 2);
    const int bm = mb * 128, bn = nb_ * 128;
    const int kbase = s * 4096;

    const int tid = threadIdx.x;
    const int w = tid >> 6, lane = tid & 63;
    const int wr = w >> 1, wc = w & 1;
    const int l31 = lane & 31, h = lane >> 5;

    f32x16 acc[2][2] = {};

    const u8* gp[4]; const u8* gv[4]; int lda[4];
    #pragma unroll
    for (int i = 0; i < 4; i++) {
        int lo = i * 4096 + tid * 16;
        int r  = lo >> 7;
        int gs = ((lo >> 4) & 7) ^ (r & 7);
        lda[i] = lo;
        gp[i] = P  + (size_t)(bm + r) * NROWS + kbase + gs * 16;
        gv[i] = vt + (size_t)(bn + r) * NROWS + kbase + gs * 16;
    }
    int offA[2][2][2], offB[2][2][2];
    #pragma unroll
    for (int t = 0; t < 2; t++) {
        int rowA = wr * 64 + t * 32 + l31;
        int rowB = wc * 64 + t * 32 + l31;
        #pragma unroll
        for (int ks = 0; ks < 2; ks++)
            #pragma unroll
            for (int j = 0; j < 2; j++) {
                offA[t][ks][j] = rowA * 128 + (((ks * 4 + h * 2 + j) ^ (rowA & 7)) << 4);
                offB[t][ks][j] = 16384 + rowB * 128 + (((ks * 4 + h * 2 + j) ^ (rowB & 7)) << 4);
            }
    }

    for (int it = 0; it < 32; it++) {
        __syncthreads();
        #pragma unroll
        for (int i = 0; i < 4; i++) ld16(gp[i], smem + lda[i]);
        #pragma unroll
        for (int i = 0; i < 4; i++) ld16(gv[i], smem + 16384 + lda[i]);
        #pragma unroll
        for (int i = 0; i < 4; i++) { gp[i] += 128; gv[i] += 128; }
        __syncthreads();
        #pragma unroll
        for (int ks = 0; ks < 2; ks++) {
            op32 A[2], B[2];
            #pragma unroll
            for (int t = 0; t < 2; t++) {
                A[t].h[0] = *(const int4v*)(smem + offA[t][ks][0]);
                A[t].h[1] = *(const int4v*)(smem + offA[t][ks][1]);
                B[t].h[0] = *(const int4v*)(smem + offB[t][ks][0]);
                B[t].h[1] = *(const int4v*)(smem + offB[t][ks][1]);
            }
            #pragma unroll
            for (int ti = 0; ti < 2; ti++)
                #pragma unroll
                for (int tj = 0; tj < 2; tj++)
                    acc[ti][tj] = __builtin_amdgcn_mfma_scale_f32_32x32x64_f8f6f4(
                        A[ti].v, B[tj].v, acc[ti][tj], 0, 0, 0, SONE, 0, SONE);
        }
    }

    // ---- epilogue: direct coalesced fp32 partial stores (cols contiguous in lane) ----
    float* ob = part + (size_t)s * NROWS * DIM + (size_t)bm * DIM + bn;
    #pragma unroll
    for (int ti = 0; ti < 2; ti++) {
        const int rb = wr * 64 + ti * 32 + 4 * h;
        #pragma unroll
        for (int rg = 0; rg < 16; rg++) {
            const int row = rb + (rg & 3) + ((rg >> 2) << 3);
            #pragma unroll
            for (int tj = 0; tj < 2; tj++)
                ob[(size_t)row * DIM + wc * 64 + tj * 32 + l31] = acc[ti][tj][rg];
        }
    }
}

// ================= kernel 4: out = (part0 + part1) * 1/(rowsum + eps) =================
// 1024 blocks (8 rows each); rowsum gather over 64 lanes + shfl reduce. (unchanged)
__global__ __launch_bounds__(256) void reduce_kernel(
    const float* __restrict__ part, const float* __restrict__ rs_part,
    float* __restrict__ out)
{
    __shared__ float inv_l[8];
    const int r0 = blockIdx.x * 8;
    const int tid = threadIdx.x;
    if (tid < 64) {
        const int rr = tid >> 3, bg = tid & 7;
        float ssum = 0.f;
        #pragma unroll
        for (int b = 0; b < 8; b++)
            ssum += rs_part[(size_t)(bg * 8 + b) * NROWS + r0 + rr];
        ssum += __shfl_xor(ssum, 1);
        ssum += __shfl_xor(ssum, 2);
        ssum += __shfl_xor(ssum, 4);
        if (bg == 0) inv_l[rr] = 1.0f / (ssum + EPSF);
    }
    __syncthreads();
    const int r = r0 + (tid >> 5);
    const int c0 = (tid & 31) * 16;
    const float inv = inv_l[tid >> 5];
    const size_t base = (size_t)r * DIM + c0;
    const size_t NS = (size_t)NROWS * DIM;
    #pragma unroll
    for (int jj = 0; jj < 4; jj++) {
        float4 a0 = *(const float4*)(part + 0 * NS + base + jj * 4);
        float4 a1 = *(const float4*)(part + 1 * NS + base + jj * 4);
        float4 o;
        o.x = (a0.x + a1.x) * inv;
        o.y = (a0.y + a1.y) * inv;
        o.z = (a0.z + a1.z) * inv;
        o.w = (a0.w + a1.w) * inv;
        *(float4*)(out + base + jj * 4) = o;
    }
}

extern "C" void kernel_launch(void* const* d_in, const int* in_sizes, int n_in,
                              void* d_out, int out_size, void* d_ws, size_t ws_size,
                              hipStream_t stream) {
    const float* x  = (const float*)d_in[0];
    const float* Wq = (const float*)d_in[1];
    const float* Wk = (const float*)d_in[2];
    const float* Wv = (const float*)d_in[3];
    float* out = (float*)d_out;

    const size_t XN = (size_t)NROWS * DIM;       // 4.19M elems
    char* ws = (char*)d_ws;
    // layout (bytes):
    //   [0,4M)    q (fp8)    [4M,8M)  k (fp8)    [8M,12M)  vt (fp8)
    //   [12M,14M) rs_part (f32, 64x8192)
    //   [14M,46M) part (f32, 2x8192x512)
    //   [64M,128M) P (fp8, 8192x8192) -- aliases xh/wth (dead after proj)
    u8*    q       = (u8*)(ws);
    u8*    kk      = (u8*)(ws + XN);
    u8*    vt      = (u8*)(ws + 2 * XN);
    float* rs_part = (float*)(ws + 3 * XN);
    float* part    = (float*)(ws + 3 * XN + (64 * NROWS * 4));
    u8*    P       = (u8*)(ws + 64ull * 1024 * 1024);
    u16*   xh      = (u16*)P;
    u16*   wth     = xh + XN;

    cvt_kernel<<<XN / 2048, 256, 0, stream>>>(x, xh);
    wcvt_kernel<<<dim3(8, 8, 3), 256, 0, stream>>>(Wq, Wk, Wv, wth);
    proj_kernel<<<dim3(4, 64, 3), 256, 0, stream>>>(xh, wth, q, kk, vt);
    score_kernel<<<2048, 512, 0, stream>>>(q, kk, P, rs_part);
    pv_kernel<<<512, 256, 0, stream>>>(P, vt, part);
    reduce_kernel<<<1024, 256, 0, stream>>>(part, rs_part, out);
}